// Round 14
// baseline (77.271 us; speedup 1.0000x reference)
//
#include <hip/hip_runtime.h>
#include <stdint.h>

// Fused softmax + top-8 (renormalized) over 64 experts.
// 1 wave = 2 tiles x 8 tokens; 8 lanes/token; 8 logits/lane. Single kernel.
// A/B vs R13: stores are now REGULAR (no nontemporal flag); tei written as
// one float2 store per lane (ramp spans both tiles). Loads stay regular
// (R13's win). Fast path: 32-bit packed keys (mono & ~63) | (63-expert_id)
// through a vcc-free u32 max/min network (sort-8 + 3 DPP merge levels).
// Exact-tie detector (conservative) -> rare wave-uniform u64-key fallback
// (exact jax.lax.top_k stable tie-break).

typedef float f32x4 __attribute__((ext_vector_type(4)));
typedef float f32x2 __attribute__((ext_vector_type(2)));

#define DPP_QUAD_XOR1   0xB1   // quad_perm(1,0,3,2)  : lane ^ 1
#define DPP_QUAD_XOR2   0x4E   // quad_perm(2,3,0,1)  : lane ^ 2
#define DPP_HALF_MIRROR 0x141  // row_half_mirror     : lane <-> 7-lane (in 8)

template<int CTRL>
static __device__ __forceinline__ uint32_t dpp32(uint32_t x) {
    return (uint32_t)__builtin_amdgcn_update_dpp(0, (int)x, CTRL, 0xF, 0xF, true);
}
template<int CTRL>
static __device__ __forceinline__ uint64_t dpp64(uint64_t x) {
    int lo = __builtin_amdgcn_update_dpp(0, (int)(uint32_t)x,         CTRL, 0xF, 0xF, true);
    int hi = __builtin_amdgcn_update_dpp(0, (int)(uint32_t)(x >> 32), CTRL, 0xF, 0xF, true);
    return ((uint64_t)(uint32_t)hi << 32) | (uint32_t)lo;
}
template<int CTRL>
static __device__ __forceinline__ float dppf(float x) {
    int i = __builtin_amdgcn_update_dpp(0, __float_as_int(x), CTRL, 0xF, 0xF, true);
    return __int_as_float(i);
}

// vcc-free compare-exchange desc on u32 (v_max_u32 + v_min_u32)
#define CE32(x, y) { uint32_t gt_ = (x > y) ? x : y; uint32_t lt_ = (x > y) ? y : x; \
                     x = gt_; y = lt_; }
// u64 CE (rare fallback only)
#define CEU(x, y) { uint64_t a_ = x, b_ = y; bool c_ = a_ < b_; \
                    x = c_ ? b_ : a_; y = c_ ? a_ : b_; }

template<int CTRL>
static __device__ __forceinline__ void merge_u32(uint32_t k[8]) {
    uint32_t m[8];
#pragma unroll
    for (int i = 0; i < 8; ++i) {
        uint32_t p = dpp32<CTRL>(k[7 - i]);
        m[i] = (k[i] > p) ? k[i] : p;      // v_max_u32
    }
    CE32(m[0], m[4]) CE32(m[1], m[5]) CE32(m[2], m[6]) CE32(m[3], m[7])
    CE32(m[0], m[2]) CE32(m[1], m[3]) CE32(m[4], m[6]) CE32(m[5], m[7])
    CE32(m[0], m[1]) CE32(m[2], m[3]) CE32(m[4], m[5]) CE32(m[6], m[7])
#pragma unroll
    for (int i = 0; i < 8; ++i) k[i] = m[i];
}

static __device__ __forceinline__ uint32_t mono(float v) {
    uint32_t u = __float_as_uint(v);
    return u ^ (uint32_t)(((int32_t)u >> 31) | 0x80000000);   // ascending map
}
static __device__ __forceinline__ float unmono(uint32_t m) {
    uint32_t u = (m & 0x80000000u) ? (m ^ 0x80000000u) : ~m;
    return __uint_as_float(u);
}
// mask ? b : a  -> v_bfi_b32
static __device__ __forceinline__ uint32_t bsel(uint32_t mask, uint32_t b, uint32_t a) {
    return (mask & b) | (~mask & a);
}

static __device__ __forceinline__ void process_tile(
    const f32x4* __restrict__ src,   // lane-adjusted pointer (for rare reload)
    f32x4 a, f32x4 b, int sub,
    float* __restrict__ out_w, float* __restrict__ out_id,
    long oi, bool act)
{
    const uint32_t cb = (uint32_t)(63 - sub * 8);

    // packed keys + detector-sufficient originals (q = mono|63)
    uint32_t k[8], q[8];
    {
        const float vals[8] = {a.x, a.y, a.z, a.w, b.x, b.y, b.z, b.w};
#pragma unroll
        for (int j = 0; j < 8; ++j) {
            uint32_t m = mono(vals[j]);
            k[j] = (m & 0xFFFFFFC0u) | (cb - (uint32_t)j);
            q[j] = m | 63u;
        }
    }

    // sort lane's 8 keys desc (Batcher, 19 CE)
    CE32(k[0],k[1]) CE32(k[2],k[3]) CE32(k[4],k[5]) CE32(k[6],k[7])
    CE32(k[0],k[2]) CE32(k[1],k[3]) CE32(k[4],k[6]) CE32(k[5],k[7])
    CE32(k[1],k[2]) CE32(k[5],k[6])
    CE32(k[0],k[4]) CE32(k[1],k[5]) CE32(k[2],k[6]) CE32(k[3],k[7])
    CE32(k[2],k[4]) CE32(k[3],k[5])
    CE32(k[1],k[2]) CE32(k[3],k[4]) CE32(k[5],k[6])

    // 3-level symmetric merge: all lanes end with token's top-8 desc
    merge_u32<DPP_QUAD_XOR1>(k);
    merge_u32<DPP_QUAD_XOR2>(k);
    merge_u32<DPP_HALF_MIRROR>(k);

    // exact conservative collision detector
    const uint32_t k7 = k[7];
    uint32_t qcnt = 0;
#pragma unroll
    for (int j = 0; j < 8; ++j)
        qcnt += (q[j] >= k7) ? 1u : 0u;          // v26[j] >= v26(k7)
    qcnt += dpp32<DPP_QUAD_XOR1>(qcnt);
    qcnt += dpp32<DPP_QUAD_XOR2>(qcnt);
    qcnt += dpp32<DPP_HALF_MIRROR>(qcnt);
    uint32_t dmin = 0xFFFFFFFFu;
#pragma unroll
    for (int i = 0; i < 7; ++i) {
        uint32_t d = (k[i] ^ k[i + 1]) >> 6;
        dmin = (d < dmin) ? d : dmin;
    }

    // own-slot key via bfi select tree (vcc-free)
    const uint32_t m1 = 0u - (uint32_t)(sub & 1);
    const uint32_t m2 = 0u - (uint32_t)((sub >> 1) & 1);
    const uint32_t m4 = 0u - (uint32_t)((sub >> 2) & 1);
    uint32_t t4a = bsel(m4, k[4], k[0]);
    uint32_t t4b = bsel(m4, k[5], k[1]);
    uint32_t t4c = bsel(m4, k[6], k[2]);
    uint32_t t4d = bsel(m4, k[7], k[3]);
    uint32_t t2a = bsel(m2, t4c, t4a);
    uint32_t t2b = bsel(m2, t4d, t4b);
    uint32_t sel = bsel(m1, t2b, t2a);

    uint32_t selmono = sel  & 0xFFFFFFC0u;
    uint32_t maxmono = k[0] & 0xFFFFFFC0u;
    int      idx     = 63 - (int)(sel & 63u);

    // rare exact redo (wave-uniform): reload inputs, u64-key extraction
    if (__any((qcnt != 8u) || (dmin == 0u))) {
        f32x4 ra = src[0];
        f32x4 rb = src[1];
        const float rv[8] = {ra.x, ra.y, ra.z, ra.w, rb.x, rb.y, rb.z, rb.w};
        uint64_t kk[8];
#pragma unroll
        for (int j = 0; j < 8; ++j)
            kk[j] = ((uint64_t)mono(rv[j]) << 6) | (uint64_t)(cb - (uint32_t)j);

        CEU(kk[0],kk[1]) CEU(kk[2],kk[3]) CEU(kk[4],kk[5]) CEU(kk[6],kk[7])
        CEU(kk[0],kk[2]) CEU(kk[1],kk[3]) CEU(kk[4],kk[6]) CEU(kk[5],kk[7])
        CEU(kk[1],kk[2]) CEU(kk[5],kk[6])
        CEU(kk[0],kk[4]) CEU(kk[1],kk[5]) CEU(kk[2],kk[6]) CEU(kk[3],kk[7])
        CEU(kk[2],kk[4]) CEU(kk[3],kk[5])
        CEU(kk[1],kk[2]) CEU(kk[3],kk[4]) CEU(kk[5],kk[6])

        uint64_t mykey = 0, mtop = 0;
#pragma unroll
        for (int r = 0; r < 8; ++r) {
            uint64_t w = kk[0];
            { uint64_t t = dpp64<DPP_QUAD_XOR1>(w);   if (t > w) w = t; }
            { uint64_t t = dpp64<DPP_QUAD_XOR2>(w);   if (t > w) w = t; }
            { uint64_t t = dpp64<DPP_HALF_MIRROR>(w); if (t > w) w = t; }
            if (r == 0)   mtop  = w;
            if (sub == r) mykey = w;
            bool pop = (kk[0] == w);   // unique keys -> one lane per group pops
            kk[0] = pop ? kk[1] : kk[0];
            kk[1] = pop ? kk[2] : kk[1];
            kk[2] = pop ? kk[3] : kk[2];
            kk[3] = pop ? kk[4] : kk[3];
            kk[4] = pop ? kk[5] : kk[4];
            kk[5] = pop ? kk[6] : kk[5];
            kk[6] = pop ? kk[7] : kk[6];
            kk[7] = pop ? 0     : kk[7];
        }
        selmono = (uint32_t)(mykey >> 6);
        maxmono = (uint32_t)(mtop  >> 6);
        idx = 63 - (int)((uint32_t)mykey & 63u);
    }

    // renormalized softmax over the selected 8
    const float v  = unmono(selmono);
    const float mv = unmono(maxmono);
    float e = __expf(v - mv);
    float s = e;
    s += dppf<DPP_QUAD_XOR1>(s);
    s += dppf<DPP_QUAD_XOR2>(s);
    s += dppf<DPP_HALF_MIRROR>(s);
    float wgt = e * __builtin_amdgcn_rcpf(s);

    if (act) {
        out_w[oi]  = wgt;          // regular stores (A/B vs R13's nt)
        out_id[oi] = (float)idx;
    }
}

__global__ __launch_bounds__(256, 8) void topk_softmax_k(
    const float* __restrict__ logits,
    float* __restrict__ out_w,
    float* __restrict__ out_id,
    float* __restrict__ out_tei,
    int T)
{
    const int  lane = threadIdx.x & 63;
    const int  wv   = (int)(threadIdx.x >> 6);
    const long t0   = ((long)blockIdx.x * 4 + wv) * 16;   // first token (2 tiles)
    if (t0 >= T) return;

    const int  sub  = lane & 7;
    const bool act0 = (t0 +     (lane >> 3)) < T;
    const bool act1 = (t0 + 8 + (lane >> 3)) < T;

    const f32x4* base = reinterpret_cast<const f32x4*>(logits);
    const f32x4* s0 = base + (act0 ? (t0 * 16 + (long)lane * 2)       : 0);
    const f32x4* s1 = base + (act1 ? ((t0 + 8) * 16 + (long)lane * 2) : 0);

    // regular (cache-allocating) loads; issue all 4 up front
    f32x4 a0 = s0[0];
    f32x4 b0 = s0[1];
    f32x4 a1 = s1[0];
    f32x4 b1 = s1[1];

    // tei ramp for both tiles: one float2 store per lane (8B, coalesced)
    if (t0 + (lane >> 2) < T) {
        const long ti = t0 * 8 + (long)lane * 2;
        f32x2 r; r.x = (float)ti; r.y = (float)(ti + 1);
        *reinterpret_cast<f32x2*>(&out_tei[ti]) = r;
    }

    process_tile(s0, a0, b0, sub, out_w, out_id, t0 * 8 + lane,       act0);
    process_tile(s1, a1, b1, sub, out_w, out_id, (t0 + 8) * 8 + lane, act1);
}

extern "C" void kernel_launch(void* const* d_in, const int* in_sizes, int n_in,
                              void* d_out, int out_size, void* d_ws, size_t ws_size,
                              hipStream_t stream) {
    const float* logits = (const float*)d_in[0];
    const int T = in_sizes[0] / 64;

    float* outw = (float*)d_out;
    float* outi = outw + (size_t)T * 8;
    float* outt = outi + (size_t)T * 8;

    const long nwaves = ((long)T + 15) / 16;          // 16 tokens per wave
    const long blocks = (nwaves + 3) / 4;             // 4 waves per block
    hipLaunchKernelGGL(topk_softmax_k, dim3((uint32_t)blocks), dim3(256), 0, stream,
                       logits, outw, outi, outt, T);
}

// Round 15
// 68.354 us; speedup vs baseline: 1.1304x; 1.1304x over previous
//
#include <hip/hip_runtime.h>
#include <stdint.h>

// Fused softmax + top-8 (renormalized) over 64 experts.
// 1 wave = 2 tiles x 8 tokens; 8 lanes/token; 8 logits/lane. Single kernel.
// Memory config (A/B-settled): REGULAR cache-allocating loads (R13 win:
//   input goes L2/L3-resident across graph replays) + NONTEMPORAL stores
//   (R14 showed allocating stores cost ~9 us via write-allocate/RFO and
//   input eviction). tei written as one nt float2 ramp store per lane.
// Fast path: 32-bit packed keys (mono & ~63) | (63 - expert_id) through a
//   vcc-free u32 max/min network (sort-8 + 3 DPP merge levels). Winning key
//   gives expert id directly (low 6 bits); 26-bit value feeds softmax.
// Exact-tie detector (conservative): boundary collision (qcnt != 8) or
//   in-top-8 collision (adjacent v26 equal) -> rare wave-uniform fallback to
//   the R3-verified u64-key serial extraction (exact jax.lax.top_k stable
//   tie-break: lower expert index first).

typedef float f32x4 __attribute__((ext_vector_type(4)));
typedef float f32x2 __attribute__((ext_vector_type(2)));

#define DPP_QUAD_XOR1   0xB1   // quad_perm(1,0,3,2)  : lane ^ 1
#define DPP_QUAD_XOR2   0x4E   // quad_perm(2,3,0,1)  : lane ^ 2
#define DPP_HALF_MIRROR 0x141  // row_half_mirror     : lane <-> 7-lane (in 8)

template<int CTRL>
static __device__ __forceinline__ uint32_t dpp32(uint32_t x) {
    return (uint32_t)__builtin_amdgcn_update_dpp(0, (int)x, CTRL, 0xF, 0xF, true);
}
template<int CTRL>
static __device__ __forceinline__ uint64_t dpp64(uint64_t x) {
    int lo = __builtin_amdgcn_update_dpp(0, (int)(uint32_t)x,         CTRL, 0xF, 0xF, true);
    int hi = __builtin_amdgcn_update_dpp(0, (int)(uint32_t)(x >> 32), CTRL, 0xF, 0xF, true);
    return ((uint64_t)(uint32_t)hi << 32) | (uint32_t)lo;
}
template<int CTRL>
static __device__ __forceinline__ float dppf(float x) {
    int i = __builtin_amdgcn_update_dpp(0, __float_as_int(x), CTRL, 0xF, 0xF, true);
    return __int_as_float(i);
}

// vcc-free compare-exchange desc on u32 (v_max_u32 + v_min_u32)
#define CE32(x, y) { uint32_t gt_ = (x > y) ? x : y; uint32_t lt_ = (x > y) ? y : x; \
                     x = gt_; y = lt_; }
// u64 CE (rare fallback only)
#define CEU(x, y) { uint64_t a_ = x, b_ = y; bool c_ = a_ < b_; \
                    x = c_ ? b_ : a_; y = c_ ? a_ : b_; }

template<int CTRL>
static __device__ __forceinline__ void merge_u32(uint32_t k[8]) {
    uint32_t m[8];
#pragma unroll
    for (int i = 0; i < 8; ++i) {
        uint32_t p = dpp32<CTRL>(k[7 - i]);
        m[i] = (k[i] > p) ? k[i] : p;      // v_max_u32
    }
    CE32(m[0], m[4]) CE32(m[1], m[5]) CE32(m[2], m[6]) CE32(m[3], m[7])
    CE32(m[0], m[2]) CE32(m[1], m[3]) CE32(m[4], m[6]) CE32(m[5], m[7])
    CE32(m[0], m[1]) CE32(m[2], m[3]) CE32(m[4], m[5]) CE32(m[6], m[7])
#pragma unroll
    for (int i = 0; i < 8; ++i) k[i] = m[i];
}

static __device__ __forceinline__ uint32_t mono(float v) {
    uint32_t u = __float_as_uint(v);
    return u ^ (uint32_t)(((int32_t)u >> 31) | 0x80000000);   // ascending map
}
static __device__ __forceinline__ float unmono(uint32_t m) {
    uint32_t u = (m & 0x80000000u) ? (m ^ 0x80000000u) : ~m;
    return __uint_as_float(u);
}
// mask ? b : a  -> v_bfi_b32
static __device__ __forceinline__ uint32_t bsel(uint32_t mask, uint32_t b, uint32_t a) {
    return (mask & b) | (~mask & a);
}

static __device__ __forceinline__ void process_tile(
    const f32x4* __restrict__ src,   // lane-adjusted pointer (for rare reload)
    f32x4 a, f32x4 b, int sub,
    float* __restrict__ out_w, float* __restrict__ out_id,
    long oi, bool act)
{
    const uint32_t cb = (uint32_t)(63 - sub * 8);

    // packed keys + detector-sufficient originals (q = mono|63)
    uint32_t k[8], q[8];
    {
        const float vals[8] = {a.x, a.y, a.z, a.w, b.x, b.y, b.z, b.w};
#pragma unroll
        for (int j = 0; j < 8; ++j) {
            uint32_t m = mono(vals[j]);
            k[j] = (m & 0xFFFFFFC0u) | (cb - (uint32_t)j);
            q[j] = m | 63u;
        }
    }

    // sort lane's 8 keys desc (Batcher, 19 CE)
    CE32(k[0],k[1]) CE32(k[2],k[3]) CE32(k[4],k[5]) CE32(k[6],k[7])
    CE32(k[0],k[2]) CE32(k[1],k[3]) CE32(k[4],k[6]) CE32(k[5],k[7])
    CE32(k[1],k[2]) CE32(k[5],k[6])
    CE32(k[0],k[4]) CE32(k[1],k[5]) CE32(k[2],k[6]) CE32(k[3],k[7])
    CE32(k[2],k[4]) CE32(k[3],k[5])
    CE32(k[1],k[2]) CE32(k[3],k[4]) CE32(k[5],k[6])

    // 3-level symmetric merge: all lanes end with token's top-8 desc
    merge_u32<DPP_QUAD_XOR1>(k);
    merge_u32<DPP_QUAD_XOR2>(k);
    merge_u32<DPP_HALF_MIRROR>(k);

    // exact conservative collision detector
    const uint32_t k7 = k[7];
    uint32_t qcnt = 0;
#pragma unroll
    for (int j = 0; j < 8; ++j)
        qcnt += (q[j] >= k7) ? 1u : 0u;          // v26[j] >= v26(k7)
    qcnt += dpp32<DPP_QUAD_XOR1>(qcnt);
    qcnt += dpp32<DPP_QUAD_XOR2>(qcnt);
    qcnt += dpp32<DPP_HALF_MIRROR>(qcnt);
    uint32_t dmin = 0xFFFFFFFFu;
#pragma unroll
    for (int i = 0; i < 7; ++i) {
        uint32_t d = (k[i] ^ k[i + 1]) >> 6;
        dmin = (d < dmin) ? d : dmin;
    }

    // own-slot key via bfi select tree (vcc-free)
    const uint32_t m1 = 0u - (uint32_t)(sub & 1);
    const uint32_t m2 = 0u - (uint32_t)((sub >> 1) & 1);
    const uint32_t m4 = 0u - (uint32_t)((sub >> 2) & 1);
    uint32_t t4a = bsel(m4, k[4], k[0]);
    uint32_t t4b = bsel(m4, k[5], k[1]);
    uint32_t t4c = bsel(m4, k[6], k[2]);
    uint32_t t4d = bsel(m4, k[7], k[3]);
    uint32_t t2a = bsel(m2, t4c, t4a);
    uint32_t t2b = bsel(m2, t4d, t4b);
    uint32_t sel = bsel(m1, t2b, t2a);

    uint32_t selmono = sel  & 0xFFFFFFC0u;
    uint32_t maxmono = k[0] & 0xFFFFFFC0u;
    int      idx     = 63 - (int)(sel & 63u);

    // rare exact redo (wave-uniform): reload inputs, u64-key extraction
    if (__any((qcnt != 8u) || (dmin == 0u))) {
        f32x4 ra = src[0];
        f32x4 rb = src[1];
        const float rv[8] = {ra.x, ra.y, ra.z, ra.w, rb.x, rb.y, rb.z, rb.w};
        uint64_t kk[8];
#pragma unroll
        for (int j = 0; j < 8; ++j)
            kk[j] = ((uint64_t)mono(rv[j]) << 6) | (uint64_t)(cb - (uint32_t)j);

        CEU(kk[0],kk[1]) CEU(kk[2],kk[3]) CEU(kk[4],kk[5]) CEU(kk[6],kk[7])
        CEU(kk[0],kk[2]) CEU(kk[1],kk[3]) CEU(kk[4],kk[6]) CEU(kk[5],kk[7])
        CEU(kk[1],kk[2]) CEU(kk[5],kk[6])
        CEU(kk[0],kk[4]) CEU(kk[1],kk[5]) CEU(kk[2],kk[6]) CEU(kk[3],kk[7])
        CEU(kk[2],kk[4]) CEU(kk[3],kk[5])
        CEU(kk[1],kk[2]) CEU(kk[3],kk[4]) CEU(kk[5],kk[6])

        uint64_t mykey = 0, mtop = 0;
#pragma unroll
        for (int r = 0; r < 8; ++r) {
            uint64_t w = kk[0];
            { uint64_t t = dpp64<DPP_QUAD_XOR1>(w);   if (t > w) w = t; }
            { uint64_t t = dpp64<DPP_QUAD_XOR2>(w);   if (t > w) w = t; }
            { uint64_t t = dpp64<DPP_HALF_MIRROR>(w); if (t > w) w = t; }
            if (r == 0)   mtop  = w;
            if (sub == r) mykey = w;
            bool pop = (kk[0] == w);   // unique keys -> one lane per group pops
            kk[0] = pop ? kk[1] : kk[0];
            kk[1] = pop ? kk[2] : kk[1];
            kk[2] = pop ? kk[3] : kk[2];
            kk[3] = pop ? kk[4] : kk[3];
            kk[4] = pop ? kk[5] : kk[4];
            kk[5] = pop ? kk[6] : kk[5];
            kk[6] = pop ? kk[7] : kk[6];
            kk[7] = pop ? 0     : kk[7];
        }
        selmono = (uint32_t)(mykey >> 6);
        maxmono = (uint32_t)(mtop  >> 6);
        idx = 63 - (int)((uint32_t)mykey & 63u);
    }

    // renormalized softmax over the selected 8
    const float v  = unmono(selmono);
    const float mv = unmono(maxmono);
    float e = __expf(v - mv);
    float s = e;
    s += dppf<DPP_QUAD_XOR1>(s);
    s += dppf<DPP_QUAD_XOR2>(s);
    s += dppf<DPP_HALF_MIRROR>(s);
    float wgt = e * __builtin_amdgcn_rcpf(s);

    if (act) {
        __builtin_nontemporal_store(wgt,        &out_w[oi]);
        __builtin_nontemporal_store((float)idx, &out_id[oi]);
    }
}

__global__ __launch_bounds__(256, 8) void topk_softmax_k(
    const float* __restrict__ logits,
    float* __restrict__ out_w,
    float* __restrict__ out_id,
    float* __restrict__ out_tei,
    int T)
{
    const int  lane = threadIdx.x & 63;
    const int  wv   = (int)(threadIdx.x >> 6);
    const long t0   = ((long)blockIdx.x * 4 + wv) * 16;   // first token (2 tiles)
    if (t0 >= T) return;

    const int  sub  = lane & 7;
    const bool act0 = (t0 +     (lane >> 3)) < T;
    const bool act1 = (t0 + 8 + (lane >> 3)) < T;

    const f32x4* base = reinterpret_cast<const f32x4*>(logits);
    const f32x4* s0 = base + (act0 ? (t0 * 16 + (long)lane * 2)       : 0);
    const f32x4* s1 = base + (act1 ? ((t0 + 8) * 16 + (long)lane * 2) : 0);

    // regular (cache-allocating) loads; issue all 4 up front
    f32x4 a0 = s0[0];
    f32x4 b0 = s0[1];
    f32x4 a1 = s1[0];
    f32x4 b1 = s1[1];

    // tei ramp for both tiles: one nt float2 store per lane (8B, coalesced)
    if (t0 + (lane >> 2) < T) {
        const long ti = t0 * 8 + (long)lane * 2;
        f32x2 r; r.x = (float)ti; r.y = (float)(ti + 1);
        __builtin_nontemporal_store(r, reinterpret_cast<f32x2*>(&out_tei[ti]));
    }

    process_tile(s0, a0, b0, sub, out_w, out_id, t0 * 8 + lane,       act0);
    process_tile(s1, a1, b1, sub, out_w, out_id, (t0 + 8) * 8 + lane, act1);
}

extern "C" void kernel_launch(void* const* d_in, const int* in_sizes, int n_in,
                              void* d_out, int out_size, void* d_ws, size_t ws_size,
                              hipStream_t stream) {
    const float* logits = (const float*)d_in[0];
    const int T = in_sizes[0] / 64;

    float* outw = (float*)d_out;
    float* outi = outw + (size_t)T * 8;
    float* outt = outi + (size_t)T * 8;

    const long nwaves = ((long)T + 15) / 16;          // 16 tokens per wave
    const long blocks = (nwaves + 3) / 4;             // 4 waves per block
    hipLaunchKernelGGL(topk_softmax_k, dim3((uint32_t)blocks), dim3(256), 0, stream,
                       logits, outw, outi, outt, T);
}